// Round 1
// baseline (444.493 us; speedup 1.0000x reference)
//
#include <hip/hip_runtime.h>
#include <cstdint>

#define DEVI __device__ __forceinline__

typedef unsigned short u16;
typedef __attribute__((ext_vector_type(4))) float f32x4;
typedef __attribute__((ext_vector_type(8))) __bf16 bf16x8;

constexpr int kB = 8, kC = 384, kN = 2304, kNH = 6, kD = 64;
constexpr int kM = kB * kN;   // 18432
constexpr int k3C = 3 * kC;   // 1152

DEVI float bf2f(u16 u) {
  union { unsigned int u; float f; } v; v.u = ((unsigned int)u) << 16; return v.f;
}
DEVI u16 f2bf(float f) {
  union { float f; unsigned int u; } v; v.f = f;
  return (u16)((v.u + 0x7fffu + ((v.u >> 16) & 1u)) >> 16);
}
DEVI void gload16(const void* g, void* l) {
  __builtin_amdgcn_global_load_lds(
      (__attribute__((address_space(1))) void*)const_cast<void*>(g),
      (__attribute__((address_space(3))) void*)l, 16, 0, 0);
}
DEVI bf16x8 ldg8(const u16* p) { return *reinterpret_cast<const bf16x8*>(p); }

// ---------------- LayerNorm: x[B,C,N] -> t_norm bf16 [B*N, C] ----------------
__global__ __launch_bounds__(256) void ln_kernel(const float* __restrict__ x,
                                                 u16* __restrict__ tn) {
  const int b = blockIdx.x / (kN / 64);
  const int n0 = (blockIdx.x % (kN / 64)) * 64;
  const int t = threadIdx.x;
  const int tni = t & 63, tc = t >> 6;
  const float* xb = x + (size_t)b * kC * kN;

  float sum = 0.f, ssq = 0.f;
  for (int c = tc; c < kC; c += 4) {
    float v = xb[(size_t)c * kN + n0 + tni];
    sum += v; ssq += v * v;
  }
  __shared__ float red[8][64];
  red[tc][tni] = sum; red[tc + 4][tni] = ssq;
  __syncthreads();
  __shared__ float s_mu[64], s_rs[64];
  if (t < 64) {
    float s = red[0][t] + red[1][t] + red[2][t] + red[3][t];
    float q = red[4][t] + red[5][t] + red[6][t] + red[7][t];
    float mu = s * (1.f / kC);
    float var = q * (1.f / kC) - mu * mu;
    s_mu[t] = mu; s_rs[t] = rsqrtf(var + 1e-5f);
  }
  __syncthreads();
  __shared__ float tile[64][65];
  for (int c0 = 0; c0 < kC; c0 += 64) {
#pragma unroll
    for (int kk = 0; kk < 16; ++kk) {
      int cl = tc * 16 + kk;
      tile[tni][cl] = xb[(size_t)(c0 + cl) * kN + n0 + tni];
    }
    __syncthreads();
#pragma unroll
    for (int kk = 0; kk < 16; ++kk) {
      int nl = tc * 16 + kk;
      float v = (tile[nl][tni] - s_mu[nl]) * s_rs[nl];
      tn[((size_t)b * kN + n0 + nl) * kC + c0 + tni] = f2bf(v);
    }
    __syncthreads();
  }
}

// ---------------- cast weights to bf16 ----------------
__global__ __launch_bounds__(256) void cast_w(const float* __restrict__ W1, const float* __restrict__ W2,
                                              u16* __restrict__ w1b, u16* __restrict__ w2b) {
  int i = blockIdx.x * 256 + threadIdx.x;
  if (i < k3C * kC) w1b[i] = f2bf(W1[i]);
  if (i < kC * kC)  w2b[i] = f2bf(W2[i]);
}

// ---------------- shared 128x128 GEMM core, K=384, both operands K-contiguous ----------------
DEVI void gemm_core(const u16* __restrict__ A, const u16* __restrict__ Bm,
                    f32x4 acc[4][4], u16* lAs, u16* lBs) {
  const int t = threadIdx.x;
  const int lane = t & 63;
  const int w = t >> 6, wr = w >> 1, wc = w & 1;
  const int lr = lane & 15, lg = lane >> 4;
  for (int kt = 0; kt < kC; kt += 64) {
    __syncthreads();
#pragma unroll
    for (int r2 = 0; r2 < 4; ++r2) {
      int e = r2 * 256 + t;
      int row = e >> 3, k8 = (e & 7) * 8;
      size_t ldsoff = (size_t)(r2 * 256 + (t & 192)) * 8;  // wave-uniform base
      gload16(A  + (size_t)row * kC + kt + k8, lAs + ldsoff);
      gload16(Bm + (size_t)row * kC + kt + k8, lBs + ldsoff);
    }
    __syncthreads();
#pragma unroll
    for (int kk = 0; kk < 2; ++kk) {
      bf16x8 af[4], bfr[4];
#pragma unroll
      for (int f = 0; f < 4; ++f)
        af[f] = ldg8(&lAs[(wr * 64 + f * 16 + lr) * 64 + kk * 32 + lg * 8]);
#pragma unroll
      for (int f = 0; f < 4; ++f)
        bfr[f] = ldg8(&lBs[(wc * 64 + f * 16 + lr) * 64 + kk * 32 + lg * 8]);
#pragma unroll
      for (int fm = 0; fm < 4; ++fm)
#pragma unroll
        for (int fn = 0; fn < 4; ++fn)
          acc[fm][fn] = __builtin_amdgcn_mfma_f32_16x16x32_bf16(af[fm], bfr[fn], acc[fm][fn], 0, 0, 0);
    }
  }
}

// ---------------- QKV GEMM: tn[M,384] x W1^T -> q,k,v bf16 [B,h,N,d] ----------------
__global__ __launch_bounds__(256) void qkv_kernel(const u16* __restrict__ tn, const u16* __restrict__ w1b,
                                                  const float* __restrict__ b1,
                                                  u16* __restrict__ q, u16* __restrict__ kbuf,
                                                  u16* __restrict__ v) {
  __shared__ u16 lAs[128 * 64], lBs[128 * 64];
  const int m0 = blockIdx.x * 128, o0 = blockIdx.y * 128;
  f32x4 acc[4][4] = {};
  gemm_core(tn + (size_t)m0 * kC, w1b + (size_t)o0 * kC, acc, lAs, lBs);

  const int t = threadIdx.x, lane = t & 63, w = t >> 6;
  const int wr = w >> 1, wc = w & 1, lr = lane & 15, lg = lane >> 4;
#pragma unroll
  for (int fm = 0; fm < 4; ++fm)
#pragma unroll
    for (int fn = 0; fn < 4; ++fn) {
      int o = o0 + wc * 64 + fn * 16 + lr;
#pragma unroll
      for (int r = 0; r < 4; ++r) {
        int m = m0 + wr * 64 + fm * 16 + lg * 4 + r;
        int b = m / kN, n = m % kN;
        float val = acc[fm][fn][r] + b1[o];
        if (o < kC) {
          int h = o >> 6, dd = o & 63;
          q[(((size_t)b * kNH + h) * kN + n) * kD + dd] = f2bf(val * 0.125f);
        } else if (o < 2 * kC) {
          int o2 = o - kC, h = o2 >> 6, dd = o2 & 63;
          kbuf[(((size_t)b * kNH + h) * kN + n) * kD + dd] = f2bf(val);
        } else {
          int o2 = o - 2 * kC, h = o2 >> 6, dd = o2 & 63;
          v[(((size_t)b * kNH + h) * kN + n) * kD + dd] = f2bf(val);
        }
      }
    }
}

// ---------------- transpose V: [bh, N, 64] -> [bh, 64, N] ----------------
__global__ __launch_bounds__(256) void vt_kernel(const u16* __restrict__ v, u16* __restrict__ vT) {
  __shared__ u16 tile[64][66];
  const int bh = blockIdx.x, n0 = blockIdx.y * 64;
  const int t = threadIdx.x, tni = t & 63, tc = t >> 6;
  const u16* vb = v + (size_t)bh * kN * kD;
#pragma unroll
  for (int kk = 0; kk < 16; ++kk) {
    int nl = tc * 16 + kk;
    tile[nl][tni] = vb[(size_t)(n0 + nl) * kD + tni];
  }
  __syncthreads();
  u16* vTb = vT + (size_t)bh * kD * kN;
#pragma unroll
  for (int kk = 0; kk < 16; ++kk) {
    int dd = tc * 16 + kk;
    vTb[(size_t)dd * kN + n0 + tni] = tile[tni][dd];
  }
}

// ---------------- flash attention: per (bh, 128 q rows); k-tiles of 64 ----------------
__global__ __launch_bounds__(256) void attn_kernel(const u16* __restrict__ qg, const u16* __restrict__ kg,
                                                   const u16* __restrict__ vT, u16* __restrict__ obuf) {
  const int bh = blockIdx.y;
  const int b = bh / kNH, h = bh % kNH;
  const int q0 = blockIdx.x * 128;
  const int t = threadIdx.x, lane = t & 63, w = t >> 6;
  const int lr = lane & 15, lg = lane >> 4;
  const u16* qb = qg + (size_t)bh * kN * kD;
  const u16* kb = kg + (size_t)bh * kN * kD;
  const u16* vb = vT + (size_t)bh * kD * kN;

  bf16x8 qf[2][2];
#pragma unroll
  for (int fm = 0; fm < 2; ++fm)
#pragma unroll
    for (int kk = 0; kk < 2; ++kk)
      qf[fm][kk] = ldg8(&qb[(size_t)(q0 + w * 32 + fm * 16 + lr) * kD + kk * 32 + lg * 8]);

  f32x4 oacc[2][4] = {};
  float mrun[2][4], lrun[2][4];
#pragma unroll
  for (int fm = 0; fm < 2; ++fm)
#pragma unroll
    for (int r = 0; r < 4; ++r) { mrun[fm][r] = -1e30f; lrun[fm][r] = 0.f; }

  __shared__ u16 p_lds[4][32 * 72];
  u16* pw = p_lds[w];

  for (int kt = 0; kt < kN; kt += 64) {
    f32x4 s[2][4] = {};
#pragma unroll
    for (int kk = 0; kk < 2; ++kk) {
      bf16x8 kf[4];
#pragma unroll
      for (int fn = 0; fn < 4; ++fn)
        kf[fn] = ldg8(&kb[(size_t)(kt + fn * 16 + lr) * kD + kk * 32 + lg * 8]);
#pragma unroll
      for (int fm = 0; fm < 2; ++fm)
#pragma unroll
        for (int fn = 0; fn < 4; ++fn)
          s[fm][fn] = __builtin_amdgcn_mfma_f32_16x16x32_bf16(qf[fm][kk], kf[fn], s[fm][fn], 0, 0, 0);
    }
    // online softmax (rows live in 16-lane groups; regs r are 4 rows per lane)
#pragma unroll
    for (int fm = 0; fm < 2; ++fm) {
      float mx[4], rs[4], al[4];
#pragma unroll
      for (int r = 0; r < 4; ++r)
        mx[r] = fmaxf(fmaxf(s[fm][0][r], s[fm][1][r]), fmaxf(s[fm][2][r], s[fm][3][r]));
#pragma unroll
      for (int off = 1; off < 16; off <<= 1)
#pragma unroll
        for (int r = 0; r < 4; ++r) mx[r] = fmaxf(mx[r], __shfl_xor(mx[r], off, 64));
#pragma unroll
      for (int r = 0; r < 4; ++r) {
        float mn = fmaxf(mrun[fm][r], mx[r]);
        al[r] = __expf(mrun[fm][r] - mn);
        mrun[fm][r] = mn;
        rs[r] = 0.f;
      }
#pragma unroll
      for (int fn = 0; fn < 4; ++fn)
#pragma unroll
        for (int r = 0; r < 4; ++r) {
          float p = __expf(s[fm][fn][r] - mrun[fm][r]);
          s[fm][fn][r] = p;
          rs[r] += p;
        }
#pragma unroll
      for (int off = 1; off < 16; off <<= 1)
#pragma unroll
        for (int r = 0; r < 4; ++r) rs[r] += __shfl_xor(rs[r], off, 64);
#pragma unroll
      for (int r = 0; r < 4; ++r) lrun[fm][r] = lrun[fm][r] * al[r] + rs[r];
#pragma unroll
      for (int dn = 0; dn < 4; ++dn)
#pragma unroll
        for (int r = 0; r < 4; ++r) oacc[fm][dn][r] *= al[r];
#pragma unroll
      for (int fn = 0; fn < 4; ++fn)
#pragma unroll
        for (int r = 0; r < 4; ++r)
          pw[(fm * 16 + lg * 4 + r) * 72 + fn * 16 + lr] = f2bf(s[fm][fn][r]);
    }
    // PV: O += P[32x64] * V[64x64]   (per-wave LDS, no block barrier needed)
#pragma unroll
    for (int kk = 0; kk < 2; ++kk) {
      bf16x8 pf[2], vf[4];
#pragma unroll
      for (int fm = 0; fm < 2; ++fm)
        pf[fm] = ldg8(&pw[(fm * 16 + lr) * 72 + kk * 32 + lg * 8]);
#pragma unroll
      for (int dn = 0; dn < 4; ++dn)
        vf[dn] = ldg8(&vb[(size_t)(dn * 16 + lr) * kN + kt + kk * 32 + lg * 8]);
#pragma unroll
      for (int fm = 0; fm < 2; ++fm)
#pragma unroll
        for (int dn = 0; dn < 4; ++dn)
          oacc[fm][dn] = __builtin_amdgcn_mfma_f32_16x16x32_bf16(pf[fm], vf[dn], oacc[fm][dn], 0, 0, 0);
    }
  }
#pragma unroll
  for (int fm = 0; fm < 2; ++fm)
#pragma unroll
    for (int dn = 0; dn < 4; ++dn)
#pragma unroll
      for (int r = 0; r < 4; ++r) {
        int row = q0 + w * 32 + fm * 16 + lg * 4 + r;
        obuf[((size_t)b * kN + row) * kC + h * 64 + dn * 16 + lr] =
            f2bf(oacc[fm][dn][r] / lrun[fm][r]);
      }
}

// ---------------- proj (transposed): out[b,c,n] = sum_k W2[c,k]*obuf[b,n,k] + b2[c] + tn[b,n,c] ----------------
__global__ __launch_bounds__(256) void proj_kernel(const u16* __restrict__ obuf, const u16* __restrict__ w2b,
                                                   const float* __restrict__ b2, const u16* __restrict__ tn,
                                                   float* __restrict__ out) {
  __shared__ u16 lAs[128 * 64], lBs[128 * 64];
  const int n0 = blockIdx.x * 128, c0 = blockIdx.y * 128, b = blockIdx.z;
  f32x4 acc[4][4] = {};
  gemm_core(w2b + (size_t)c0 * kC, obuf + ((size_t)b * kN + n0) * kC, acc, lAs, lBs);

  const int t = threadIdx.x, lane = t & 63, w = t >> 6;
  const int wr = w >> 1, wc = w & 1, lr = lane & 15, lg = lane >> 4;
#pragma unroll
  for (int fm = 0; fm < 4; ++fm)
#pragma unroll
    for (int fn = 0; fn < 4; ++fn) {
      int n = n0 + wc * 64 + fn * 16 + lr;
#pragma unroll
      for (int r = 0; r < 4; ++r) {
        int c = c0 + wr * 64 + fm * 16 + lg * 4 + r;
        float val = acc[fm][fn][r] + b2[c] + bf2f(tn[((size_t)b * kN + n) * kC + c]);
        out[((size_t)b * kC + c) * kN + n] = val;
      }
    }
}

extern "C" void kernel_launch(void* const* d_in, const int* in_sizes, int n_in,
                              void* d_out, int out_size, void* d_ws, size_t ws_size,
                              hipStream_t stream) {
  const float* x  = (const float*)d_in[0];
  const float* W1 = (const float*)d_in[1];
  const float* b1 = (const float*)d_in[2];
  const float* W2 = (const float*)d_in[3];
  const float* b2 = (const float*)d_in[4];
  float* out = (float*)d_out;

  const size_t nBNC = (size_t)kM * kC;  // 7,077,888 elements
  u16* tn  = (u16*)d_ws;
  u16* qb  = tn  + nBNC;
  u16* kb  = qb  + nBNC;
  u16* vb  = kb  + nBNC;
  u16* vT  = vb  + nBNC;
  u16* w1b = vT  + nBNC;
  u16* w2b = w1b + (size_t)k3C * kC;
  u16* obuf = vb;  // alias: v is dead after vt_kernel

  ln_kernel<<<dim3(kB * (kN / 64)), dim3(256), 0, stream>>>(x, tn);
  cast_w<<<dim3((k3C * kC + 255) / 256), dim3(256), 0, stream>>>(W1, W2, w1b, w2b);
  qkv_kernel<<<dim3(kM / 128, k3C / 128), dim3(256), 0, stream>>>(tn, w1b, b1, qb, kb, vb);
  vt_kernel<<<dim3(kB * kNH, kN / 64), dim3(256), 0, stream>>>(vb, vT);
  attn_kernel<<<dim3(kN / 128, kB * kNH), dim3(256), 0, stream>>>(qb, kb, vT, obuf);
  proj_kernel<<<dim3(kN / 128, kC / 128, kB), dim3(256), 0, stream>>>(obuf, w2b, b2, tn, out);
}

// Round 2
// 392.378 us; speedup vs baseline: 1.1328x; 1.1328x over previous
//
#include <hip/hip_runtime.h>
#include <cstdint>

#define DEVI __device__ __forceinline__

typedef unsigned short u16;
typedef __attribute__((ext_vector_type(2))) unsigned int u32x2;
typedef __attribute__((ext_vector_type(4))) float f32x4;
typedef __attribute__((ext_vector_type(16))) float f32x16;
typedef __attribute__((ext_vector_type(8))) __bf16 bf16x8;

constexpr int kB = 8, kC = 384, kN = 2304, kNH = 6, kD = 64;
constexpr int kM = kB * kN;   // 18432
constexpr int k3C = 3 * kC;   // 1152

DEVI float bf2f(u16 u) {
  union { unsigned int u; float f; } v; v.u = ((unsigned int)u) << 16; return v.f;
}
DEVI u16 f2bf(float f) {
  union { float f; unsigned int u; } v; v.f = f;
  return (u16)((v.u + 0x7fffu + ((v.u >> 16) & 1u)) >> 16);
}
DEVI void gload16(const void* g, void* l) {
  __builtin_amdgcn_global_load_lds(
      (__attribute__((address_space(1))) void*)const_cast<void*>(g),
      (__attribute__((address_space(3))) void*)l, 16, 0, 0);
}
DEVI bf16x8 ldg8(const u16* p) { return *reinterpret_cast<const bf16x8*>(p); }

// pack two f32 -> one u32 of 2 bf16 (RNE), low word = first arg
DEVI unsigned cvtpk(float lo, float hi) {
  unsigned r;
  asm("v_cvt_pk_bf16_f32 %0, %1, %2" : "=v"(r) : "v"(lo), "v"(hi));
  return r;
}
// exchange: a' = {a.lo, b.lo(from lane-32)}, b' = {a.hi(from lane+32), b.hi}
DEVI void plswap(unsigned& a, unsigned& b) {
#if __has_builtin(__builtin_amdgcn_permlane32_swap)
  auto rr = __builtin_amdgcn_permlane32_swap(a, b, false, false);
  a = rr[0]; b = rr[1];
#else
  unsigned ax = __shfl_xor(a, 32, 64), bx = __shfl_xor(b, 32, 64);
  int hi = (threadIdx.x & 63) >> 5;
  unsigned r0 = hi ? bx : a;
  unsigned r1 = hi ? b : ax;
  a = r0; b = r1;
#endif
}

// ---------------- LayerNorm: x[B,C,N] -> t_norm bf16 [B*N, C] ----------------
__global__ __launch_bounds__(256) void ln_kernel(const float* __restrict__ x,
                                                 u16* __restrict__ tn) {
  const int b = blockIdx.x / (kN / 64);
  const int n0 = (blockIdx.x % (kN / 64)) * 64;
  const int t = threadIdx.x;
  const int tni = t & 63, tc = t >> 6;
  const float* xb = x + (size_t)b * kC * kN;

  float sum = 0.f, ssq = 0.f;
  for (int c = tc; c < kC; c += 4) {
    float v = xb[(size_t)c * kN + n0 + tni];
    sum += v; ssq += v * v;
  }
  __shared__ float red[8][64];
  red[tc][tni] = sum; red[tc + 4][tni] = ssq;
  __syncthreads();
  __shared__ float s_mu[64], s_rs[64];
  if (t < 64) {
    float s = red[0][t] + red[1][t] + red[2][t] + red[3][t];
    float q = red[4][t] + red[5][t] + red[6][t] + red[7][t];
    float mu = s * (1.f / kC);
    float var = q * (1.f / kC) - mu * mu;
    s_mu[t] = mu; s_rs[t] = rsqrtf(var + 1e-5f);
  }
  __syncthreads();
  __shared__ float tile[64][65];
  for (int c0 = 0; c0 < kC; c0 += 64) {
#pragma unroll
    for (int kk = 0; kk < 16; ++kk) {
      int cl = tc * 16 + kk;
      tile[tni][cl] = xb[(size_t)(c0 + cl) * kN + n0 + tni];
    }
    __syncthreads();
#pragma unroll
    for (int kk = 0; kk < 16; ++kk) {
      int nl = tc * 16 + kk;
      float v = (tile[nl][tni] - s_mu[nl]) * s_rs[nl];
      tn[((size_t)b * kN + n0 + nl) * kC + c0 + tni] = f2bf(v);
    }
    __syncthreads();
  }
}

// ---------------- cast weights to bf16 ----------------
__global__ __launch_bounds__(256) void cast_w(const float* __restrict__ W1, const float* __restrict__ W2,
                                              u16* __restrict__ w1b, u16* __restrict__ w2b) {
  int i = blockIdx.x * 256 + threadIdx.x;
  if (i < k3C * kC) w1b[i] = f2bf(W1[i]);
  if (i < kC * kC)  w2b[i] = f2bf(W2[i]);
}

// ---------------- shared 128x128 GEMM core, K=384, both operands K-contiguous ----------------
DEVI void gemm_core(const u16* __restrict__ A, const u16* __restrict__ Bm,
                    f32x4 acc[4][4], u16* lAs, u16* lBs) {
  const int t = threadIdx.x;
  const int lane = t & 63;
  const int w = t >> 6, wr = w >> 1, wc = w & 1;
  const int lr = lane & 15, lg = lane >> 4;
  for (int kt = 0; kt < kC; kt += 64) {
    __syncthreads();
#pragma unroll
    for (int r2 = 0; r2 < 4; ++r2) {
      int e = r2 * 256 + t;
      int row = e >> 3, k8 = (e & 7) * 8;
      size_t ldsoff = (size_t)(r2 * 256 + (t & 192)) * 8;  // wave-uniform base
      gload16(A  + (size_t)row * kC + kt + k8, lAs + ldsoff);
      gload16(Bm + (size_t)row * kC + kt + k8, lBs + ldsoff);
    }
    __syncthreads();
#pragma unroll
    for (int kk = 0; kk < 2; ++kk) {
      bf16x8 af[4], bfr[4];
#pragma unroll
      for (int f = 0; f < 4; ++f)
        af[f] = ldg8(&lAs[(wr * 64 + f * 16 + lr) * 64 + kk * 32 + lg * 8]);
#pragma unroll
      for (int f = 0; f < 4; ++f)
        bfr[f] = ldg8(&lBs[(wc * 64 + f * 16 + lr) * 64 + kk * 32 + lg * 8]);
#pragma unroll
      for (int fm = 0; fm < 4; ++fm)
#pragma unroll
        for (int fn = 0; fn < 4; ++fn)
          acc[fm][fn] = __builtin_amdgcn_mfma_f32_16x16x32_bf16(af[fm], bfr[fn], acc[fm][fn], 0, 0, 0);
    }
  }
}

// ---------------- QKV GEMM: tn[M,384] x W1^T -> q,k,v bf16 [B,h,N,d] ----------------
__global__ __launch_bounds__(256) void qkv_kernel(const u16* __restrict__ tn, const u16* __restrict__ w1b,
                                                  const float* __restrict__ b1,
                                                  u16* __restrict__ q, u16* __restrict__ kbuf,
                                                  u16* __restrict__ v) {
  __shared__ u16 lAs[128 * 64], lBs[128 * 64];
  const int m0 = blockIdx.x * 128, o0 = blockIdx.y * 128;
  f32x4 acc[4][4] = {};
  gemm_core(tn + (size_t)m0 * kC, w1b + (size_t)o0 * kC, acc, lAs, lBs);

  const int t = threadIdx.x, lane = t & 63, w = t >> 6;
  const int wr = w >> 1, wc = w & 1, lr = lane & 15, lg = lane >> 4;
#pragma unroll
  for (int fm = 0; fm < 4; ++fm)
#pragma unroll
    for (int fn = 0; fn < 4; ++fn) {
      int o = o0 + wc * 64 + fn * 16 + lr;
#pragma unroll
      for (int r = 0; r < 4; ++r) {
        int m = m0 + wr * 64 + fm * 16 + lg * 4 + r;
        int b = m / kN, n = m % kN;
        float val = acc[fm][fn][r] + b1[o];
        if (o < kC) {
          int h = o >> 6, dd = o & 63;
          q[(((size_t)b * kNH + h) * kN + n) * kD + dd] = f2bf(val * 0.125f);
        } else if (o < 2 * kC) {
          int o2 = o - kC, h = o2 >> 6, dd = o2 & 63;
          kbuf[(((size_t)b * kNH + h) * kN + n) * kD + dd] = f2bf(val);
        } else {
          int o2 = o - 2 * kC, h = o2 >> 6, dd = o2 & 63;
          v[(((size_t)b * kNH + h) * kN + n) * kD + dd] = f2bf(val);
        }
      }
    }
}

// ---------------- transpose V: [bh, N, 64] -> [bh, 64, N] ----------------
__global__ __launch_bounds__(256) void vt_kernel(const u16* __restrict__ v, u16* __restrict__ vT) {
  __shared__ u16 tile[64][66];
  const int bh = blockIdx.x, n0 = blockIdx.y * 64;
  const int t = threadIdx.x, tni = t & 63, tc = t >> 6;
  const u16* vb = v + (size_t)bh * kN * kD;
#pragma unroll
  for (int kk = 0; kk < 16; ++kk) {
    int nl = tc * 16 + kk;
    tile[nl][tni] = vb[(size_t)(n0 + nl) * kD + tni];
  }
  __syncthreads();
  u16* vTb = vT + (size_t)bh * kD * kN;
#pragma unroll
  for (int kk = 0; kk < 16; ++kk) {
    int dd = tc * 16 + kk;
    vTb[(size_t)dd * kN + n0 + tni] = tile[tni][dd];
  }
}

// ---------------- flash attention, swapped-operand 32x32x16 form ----------------
// Each wave owns 32 q-rows; S^T = mfma(K, Q) puts a full q-row's scores in a
// lane pair (lane, lane^32). Softmax is lane-local + one shfl_xor(32).
// P goes to PV's B-fragments in-register via cvt_pk_bf16 + permlane32_swap.
// O^T = mfma(V^T, P). No LDS, no barriers.
#define PV_STEP(SV, OFF, KS)                                                          \
  {                                                                                   \
    unsigned a0 = cvtpk(SV[OFF + 0], SV[OFF + 1]);                                    \
    unsigned a1 = cvtpk(SV[OFF + 2], SV[OFF + 3]);                                    \
    unsigned a2 = cvtpk(SV[OFF + 4], SV[OFF + 5]);                                    \
    unsigned a3 = cvtpk(SV[OFF + 6], SV[OFF + 7]);                                    \
    plswap(a0, a2); plswap(a1, a3);                                                   \
    union { unsigned wds[4]; bf16x8 v; } pu;                                          \
    pu.wds[0] = a0; pu.wds[1] = a1; pu.wds[2] = a2; pu.wds[3] = a3;                   \
    bf16x8 vf0 = ldg8(&vbT[(size_t)ql * kN + kt + (KS) * 16 + hi * 8]);               \
    bf16x8 vf1 = ldg8(&vbT[(size_t)(32 + ql) * kN + kt + (KS) * 16 + hi * 8]);        \
    o0 = __builtin_amdgcn_mfma_f32_32x32x16_bf16(vf0, pu.v, o0, 0, 0, 0);             \
    o1 = __builtin_amdgcn_mfma_f32_32x32x16_bf16(vf1, pu.v, o1, 0, 0, 0);             \
  }

__global__ __launch_bounds__(256) void attn_kernel(const u16* __restrict__ qg, const u16* __restrict__ kg,
                                                   const u16* __restrict__ vT, u16* __restrict__ obuf) {
  const int bh = blockIdx.y;
  const int b = bh / kNH, h = bh % kNH;
  const int t = threadIdx.x, lane = t & 63, w = t >> 6;
  const int q0w = blockIdx.x * 128 + w * 32;
  const int ql = lane & 31;
  const int hi = lane >> 5;
  const u16* qb  = qg + (size_t)bh * kN * kD;
  const u16* kbB = kg + (size_t)bh * kN * kD;
  const u16* vbT = vT + (size_t)bh * kD * kN;

  // Q as B-fragment: Q[q0w+ql][ds*16 + hi*8 + j]
  bf16x8 qf[4];
#pragma unroll
  for (int ds = 0; ds < 4; ++ds)
    qf[ds] = ldg8(&qb[(size_t)(q0w + ql) * kD + ds * 16 + hi * 8]);

  f32x16 o0 = {}, o1 = {};
  float m = -1e30f, l = 0.f;

  for (int kt = 0; kt < kN; kt += 64) {
    // ---- S^T[k][q] = K . Q^T : s0 = k-rows [kt,kt+32), s1 = [kt+32,kt+64)
    f32x16 s0 = {}, s1 = {};
#pragma unroll
    for (int ds = 0; ds < 4; ++ds) {
      bf16x8 kf0 = ldg8(&kbB[(size_t)(kt + ql) * kD + ds * 16 + hi * 8]);
      bf16x8 kf1 = ldg8(&kbB[(size_t)(kt + 32 + ql) * kD + ds * 16 + hi * 8]);
      s0 = __builtin_amdgcn_mfma_f32_32x32x16_bf16(kf0, qf[ds], s0, 0, 0, 0);
      s1 = __builtin_amdgcn_mfma_f32_32x32x16_bf16(kf1, qf[ds], s1, 0, 0, 0);
    }
    // ---- online softmax: q-row = ql, 32 values here + 32 in lane^32
    float tmx[16];
#pragma unroll
    for (int r = 0; r < 16; ++r) tmx[r] = fmaxf(s0[r], s1[r]);
#pragma unroll
    for (int st = 8; st; st >>= 1)
#pragma unroll
      for (int r = 0; r < 8; ++r)
        if (r < st) tmx[r] = fmaxf(tmx[r], tmx[r + st]);
    float pmax = fmaxf(tmx[0], __shfl_xor(tmx[0], 32, 64));

    if (!__all(pmax - m <= 8.f)) {  // defer-max: rescale only on real growth
      float mn = fmaxf(m, pmax);
      float al = __expf(m - mn);
      m = mn;
      l *= al;
      o0 *= al;
      o1 *= al;
    }
#pragma unroll
    for (int r = 0; r < 16; ++r) {
      s0[r] = __expf(s0[r] - m);
      s1[r] = __expf(s1[r] - m);
    }
    float tsm[16];
#pragma unroll
    for (int r = 0; r < 16; ++r) tsm[r] = s0[r] + s1[r];
#pragma unroll
    for (int st = 8; st; st >>= 1)
#pragma unroll
      for (int r = 0; r < 8; ++r)
        if (r < st) tsm[r] += tsm[r + st];
    l += tsm[0] + __shfl_xor(tsm[0], 32, 64);

    // ---- PV: O^T[d][q] += V^T . P ; P fragments built in-register
    PV_STEP(s0, 0, 0)
    PV_STEP(s0, 8, 1)
    PV_STEP(s1, 0, 2)
    PV_STEP(s1, 8, 3)
  }

  const float inv = 1.f / l;
  {
    const size_t row = ((size_t)b * kN + q0w + ql) * kC + h * 64;
#pragma unroll
    for (int g = 0; g < 4; ++g) {
      u32x2 pk;
      pk.x = cvtpk(o0[g * 4 + 0] * inv, o0[g * 4 + 1] * inv);
      pk.y = cvtpk(o0[g * 4 + 2] * inv, o0[g * 4 + 3] * inv);
      *reinterpret_cast<u32x2*>(&obuf[row + g * 8 + 4 * hi]) = pk;
    }
#pragma unroll
    for (int g = 0; g < 4; ++g) {
      u32x2 pk;
      pk.x = cvtpk(o1[g * 4 + 0] * inv, o1[g * 4 + 1] * inv);
      pk.y = cvtpk(o1[g * 4 + 2] * inv, o1[g * 4 + 3] * inv);
      *reinterpret_cast<u32x2*>(&obuf[row + 32 + g * 8 + 4 * hi]) = pk;
    }
  }
}

// ---------------- proj (transposed): out[b,c,n] = sum_k W2[c,k]*obuf[b,n,k] + b2[c] + tn[b,n,c] ----------------
__global__ __launch_bounds__(256) void proj_kernel(const u16* __restrict__ obuf, const u16* __restrict__ w2b,
                                                   const float* __restrict__ b2, const u16* __restrict__ tn,
                                                   float* __restrict__ out) {
  __shared__ u16 lAs[128 * 64], lBs[128 * 64];
  const int n0 = blockIdx.x * 128, c0 = blockIdx.y * 128, b = blockIdx.z;
  f32x4 acc[4][4] = {};
  gemm_core(w2b + (size_t)c0 * kC, obuf + ((size_t)b * kN + n0) * kC, acc, lAs, lBs);

  const int t = threadIdx.x, lane = t & 63, w = t >> 6;
  const int wr = w >> 1, wc = w & 1, lr = lane & 15, lg = lane >> 4;
#pragma unroll
  for (int fm = 0; fm < 4; ++fm)
#pragma unroll
    for (int fn = 0; fn < 4; ++fn) {
      int n = n0 + wc * 64 + fn * 16 + lr;
#pragma unroll
      for (int r = 0; r < 4; ++r) {
        int c = c0 + wr * 64 + fm * 16 + lg * 4 + r;
        float val = acc[fm][fn][r] + b2[c] + bf2f(tn[((size_t)b * kN + n) * kC + c]);
        out[((size_t)b * kC + c) * kN + n] = val;
      }
    }
}

extern "C" void kernel_launch(void* const* d_in, const int* in_sizes, int n_in,
                              void* d_out, int out_size, void* d_ws, size_t ws_size,
                              hipStream_t stream) {
  const float* x  = (const float*)d_in[0];
  const float* W1 = (const float*)d_in[1];
  const float* b1 = (const float*)d_in[2];
  const float* W2 = (const float*)d_in[3];
  const float* b2 = (const float*)d_in[4];
  float* out = (float*)d_out;

  const size_t nBNC = (size_t)kM * kC;  // 7,077,888 elements
  u16* tn  = (u16*)d_ws;
  u16* qb  = tn  + nBNC;
  u16* kb  = qb  + nBNC;
  u16* vb  = kb  + nBNC;
  u16* vT  = vb  + nBNC;
  u16* w1b = vT  + nBNC;
  u16* w2b = w1b + (size_t)k3C * kC;
  u16* obuf = vb;  // alias: v is dead after vt_kernel

  ln_kernel<<<dim3(kB * (kN / 64)), dim3(256), 0, stream>>>(x, tn);
  cast_w<<<dim3((k3C * kC + 255) / 256), dim3(256), 0, stream>>>(W1, W2, w1b, w2b);
  qkv_kernel<<<dim3(kM / 128, k3C / 128), dim3(256), 0, stream>>>(tn, w1b, b1, qb, kb, vb);
  vt_kernel<<<dim3(kB * kNH, kN / 64), dim3(256), 0, stream>>>(vb, vT);
  attn_kernel<<<dim3(kN / 128, kB * kNH), dim3(256), 0, stream>>>(qb, kb, vT, obuf);
  proj_kernel<<<dim3(kN / 128, kC / 128, kB), dim3(256), 0, stream>>>(obuf, w2b, b2, tn, out);
}

// Round 3
// 226.724 us; speedup vs baseline: 1.9605x; 1.7306x over previous
//
#include <hip/hip_runtime.h>
#include <cstdint>

#define DEVI __device__ __forceinline__

typedef unsigned short u16;
typedef __attribute__((ext_vector_type(2))) unsigned int u32x2;
typedef __attribute__((ext_vector_type(4))) float f32x4;
typedef __attribute__((ext_vector_type(16))) float f32x16;
typedef __attribute__((ext_vector_type(8))) __bf16 bf16x8;

constexpr int kB = 8, kC = 384, kN = 2304, kNH = 6, kD = 64;
constexpr int kM = kB * kN;   // 18432
constexpr int k3C = 3 * kC;   // 1152
constexpr int kNT = kN / 64;  // 36 k-tiles

DEVI float bf2f(u16 u) {
  union { unsigned int u; float f; } v; v.u = ((unsigned int)u) << 16; return v.f;
}
DEVI u16 f2bf(float f) {
  union { float f; unsigned int u; } v; v.f = f;
  return (u16)((v.u + 0x7fffu + ((v.u >> 16) & 1u)) >> 16);
}
DEVI void gload16(const void* g, void* l) {
  __builtin_amdgcn_global_load_lds(
      (__attribute__((address_space(1))) void*)const_cast<void*>(g),
      (__attribute__((address_space(3))) void*)l, 16, 0, 0);
}
DEVI bf16x8 ldg8(const u16* p) { return *reinterpret_cast<const bf16x8*>(p); }

DEVI float fexp2(float x) {
#if __has_builtin(__builtin_amdgcn_exp2f)
  return __builtin_amdgcn_exp2f(x);
#else
  return exp2f(x);
#endif
}

// pack two f32 -> one u32 of 2 bf16 (RNE), low word = first arg
DEVI unsigned cvtpk(float lo, float hi) {
  unsigned r;
  asm("v_cvt_pk_bf16_f32 %0, %1, %2" : "=v"(r) : "v"(lo), "v"(hi));
  return r;
}
// exchange halves across lane<32 / lane>=32
DEVI void plswap(unsigned& a, unsigned& b) {
#if __has_builtin(__builtin_amdgcn_permlane32_swap)
  auto rr = __builtin_amdgcn_permlane32_swap(a, b, false, false);
  a = rr[0]; b = rr[1];
#else
  unsigned ax = __shfl_xor(a, 32, 64), bx = __shfl_xor(b, 32, 64);
  int hi = (threadIdx.x & 63) >> 5;
  unsigned r0 = hi ? bx : a;
  unsigned r1 = hi ? b : ax;
  a = r0; b = r1;
#endif
}

// swizzled LDS read: tile row-major [64 rows][128 B], byte col XOR'd by row key
DEVI bf16x8 ldsw(const u16* base, int row, int cb) {
  return *reinterpret_cast<const bf16x8*>(
      (const char*)base + row * 128 + (cb ^ ((row & 7) << 4)));
}

// ---------------- LayerNorm: x[B,C,N] -> t_norm bf16 [B*N, C] ----------------
__global__ __launch_bounds__(256) void ln_kernel(const float* __restrict__ x,
                                                 u16* __restrict__ tn) {
  const int b = blockIdx.x / (kN / 64);
  const int n0 = (blockIdx.x % (kN / 64)) * 64;
  const int t = threadIdx.x;
  const int tni = t & 63, tc = t >> 6;
  const float* xb = x + (size_t)b * kC * kN;

  float sum = 0.f, ssq = 0.f;
  for (int c = tc; c < kC; c += 4) {
    float v = xb[(size_t)c * kN + n0 + tni];
    sum += v; ssq += v * v;
  }
  __shared__ float red[8][64];
  red[tc][tni] = sum; red[tc + 4][tni] = ssq;
  __syncthreads();
  __shared__ float s_mu[64], s_rs[64];
  if (t < 64) {
    float s = red[0][t] + red[1][t] + red[2][t] + red[3][t];
    float q = red[4][t] + red[5][t] + red[6][t] + red[7][t];
    float mu = s * (1.f / kC);
    float var = q * (1.f / kC) - mu * mu;
    s_mu[t] = mu; s_rs[t] = rsqrtf(var + 1e-5f);
  }
  __syncthreads();
  __shared__ float tile[64][65];
  for (int c0 = 0; c0 < kC; c0 += 64) {
#pragma unroll
    for (int kk = 0; kk < 16; ++kk) {
      int cl = tc * 16 + kk;
      tile[tni][cl] = xb[(size_t)(c0 + cl) * kN + n0 + tni];
    }
    __syncthreads();
#pragma unroll
    for (int kk = 0; kk < 16; ++kk) {
      int nl = tc * 16 + kk;
      float v = (tile[nl][tni] - s_mu[nl]) * s_rs[nl];
      tn[((size_t)b * kN + n0 + nl) * kC + c0 + tni] = f2bf(v);
    }
    __syncthreads();
  }
}

// ---------------- cast weights to bf16 ----------------
__global__ __launch_bounds__(256) void cast_w(const float* __restrict__ W1, const float* __restrict__ W2,
                                              u16* __restrict__ w1b, u16* __restrict__ w2b) {
  int i = blockIdx.x * 256 + threadIdx.x;
  if (i < k3C * kC) w1b[i] = f2bf(W1[i]);
  if (i < kC * kC)  w2b[i] = f2bf(W2[i]);
}

// ---------------- shared 128x128 GEMM core, K=384, both operands K-contiguous ----------------
DEVI void gemm_core(const u16* __restrict__ A, const u16* __restrict__ Bm,
                    f32x4 acc[4][4], u16* lAs, u16* lBs) {
  const int t = threadIdx.x;
  const int lane = t & 63;
  const int w = t >> 6, wr = w >> 1, wc = w & 1;
  const int lr = lane & 15, lg = lane >> 4;
  for (int kt = 0; kt < kC; kt += 64) {
    __syncthreads();
#pragma unroll
    for (int r2 = 0; r2 < 4; ++r2) {
      int e = r2 * 256 + t;
      int row = e >> 3, k8 = (e & 7) * 8;
      size_t ldsoff = (size_t)(r2 * 256 + (t & 192)) * 8;  // wave-uniform base
      gload16(A  + (size_t)row * kC + kt + k8, lAs + ldsoff);
      gload16(Bm + (size_t)row * kC + kt + k8, lBs + ldsoff);
    }
    __syncthreads();
#pragma unroll
    for (int kk = 0; kk < 2; ++kk) {
      bf16x8 af[4], bfr[4];
#pragma unroll
      for (int f = 0; f < 4; ++f)
        af[f] = ldg8(&lAs[(wr * 64 + f * 16 + lr) * 64 + kk * 32 + lg * 8]);
#pragma unroll
      for (int f = 0; f < 4; ++f)
        bfr[f] = ldg8(&lBs[(wc * 64 + f * 16 + lr) * 64 + kk * 32 + lg * 8]);
#pragma unroll
      for (int fm = 0; fm < 4; ++fm)
#pragma unroll
        for (int fn = 0; fn < 4; ++fn)
          acc[fm][fn] = __builtin_amdgcn_mfma_f32_16x16x32_bf16(af[fm], bfr[fn], acc[fm][fn], 0, 0, 0);
    }
  }
}

// ---------------- QKV GEMM: tn[M,384] x W1^T -> q,k,v bf16 [B,h,N,d] ----------------
// q is pre-scaled by (1/sqrt(d)) * log2(e) so attention works in exp2 domain.
__global__ __launch_bounds__(256) void qkv_kernel(const u16* __restrict__ tn, const u16* __restrict__ w1b,
                                                  const float* __restrict__ b1,
                                                  u16* __restrict__ q, u16* __restrict__ kbuf,
                                                  u16* __restrict__ v) {
  __shared__ u16 lAs[128 * 64], lBs[128 * 64];
  const int m0 = blockIdx.x * 128, o0 = blockIdx.y * 128;
  f32x4 acc[4][4] = {};
  gemm_core(tn + (size_t)m0 * kC, w1b + (size_t)o0 * kC, acc, lAs, lBs);

  const int t = threadIdx.x, lane = t & 63, w = t >> 6;
  const int wr = w >> 1, wc = w & 1, lr = lane & 15, lg = lane >> 4;
  const float kQScale = 0.125f * 1.44269504088896f;
#pragma unroll
  for (int fm = 0; fm < 4; ++fm)
#pragma unroll
    for (int fn = 0; fn < 4; ++fn) {
      int o = o0 + wc * 64 + fn * 16 + lr;
#pragma unroll
      for (int r = 0; r < 4; ++r) {
        int m = m0 + wr * 64 + fm * 16 + lg * 4 + r;
        int b = m / kN, n = m % kN;
        float val = acc[fm][fn][r] + b1[o];
        if (o < kC) {
          int h = o >> 6, dd = o & 63;
          q[(((size_t)b * kNH + h) * kN + n) * kD + dd] = f2bf(val * kQScale);
        } else if (o < 2 * kC) {
          int o2 = o - kC, h = o2 >> 6, dd = o2 & 63;
          kbuf[(((size_t)b * kNH + h) * kN + n) * kD + dd] = f2bf(val);
        } else {
          int o2 = o - 2 * kC, h = o2 >> 6, dd = o2 & 63;
          v[(((size_t)b * kNH + h) * kN + n) * kD + dd] = f2bf(val);
        }
      }
    }
}

// ---------------- transpose V: [bh, N, 64] -> [bh, 64, N] ----------------
__global__ __launch_bounds__(256) void vt_kernel(const u16* __restrict__ v, u16* __restrict__ vT) {
  __shared__ u16 tile[64][66];
  const int bh = blockIdx.x, n0 = blockIdx.y * 64;
  const int t = threadIdx.x, tni = t & 63, tc = t >> 6;
  const u16* vb = v + (size_t)bh * kN * kD;
#pragma unroll
  for (int kk = 0; kk < 16; ++kk) {
    int nl = tc * 16 + kk;
    tile[nl][tni] = vb[(size_t)(n0 + nl) * kD + tni];
  }
  __syncthreads();
  u16* vTb = vT + (size_t)bh * kD * kN;
#pragma unroll
  for (int kk = 0; kk < 16; ++kk) {
    int dd = tc * 16 + kk;
    vTb[(size_t)dd * kN + n0 + tni] = tile[tni][dd];
  }
}

// ---------------- flash attention v3 ----------------
// Swapped-operand 32x32x16 MFMA; K/V tiles staged cooperatively into LDS
// (coalesced global_load_lds, XOR-swizzled layout), 2-phase double buffer.
// Softmax in exp2 domain, lane-local + one shfl_xor(32).
#define PV_STEP(SV, OFF, KS)                                                          \
  {                                                                                   \
    unsigned a0 = cvtpk(SV[OFF + 0], SV[OFF + 1]);                                    \
    unsigned a1 = cvtpk(SV[OFF + 2], SV[OFF + 3]);                                    \
    unsigned a2 = cvtpk(SV[OFF + 4], SV[OFF + 5]);                                    \
    unsigned a3 = cvtpk(SV[OFF + 6], SV[OFF + 7]);                                    \
    plswap(a0, a2); plswap(a1, a3);                                                   \
    union { unsigned wds[4]; bf16x8 v; } pu;                                          \
    pu.wds[0] = a0; pu.wds[1] = a1; pu.wds[2] = a2; pu.wds[3] = a3;                   \
    bf16x8 vf0 = ldsw(vL, ql, (KS) * 32 + hi * 16);                                   \
    bf16x8 vf1 = ldsw(vL, 32 + ql, (KS) * 32 + hi * 16);                              \
    o0 = __builtin_amdgcn_mfma_f32_32x32x16_bf16(vf0, pu.v, o0, 0, 0, 0);             \
    o1 = __builtin_amdgcn_mfma_f32_32x32x16_bf16(vf1, pu.v, o1, 0, 0, 0);             \
  }

// stage one 64-row tile (row stride `gstride` bytes) into LDS linearly,
// global source pre-XOR'd so that swizzled reads see the right data
#define STAGE(dstLds, gbase, gstride)                                                 \
  {                                                                                   \
    _Pragma("unroll")                                                                 \
    for (int c = 0; c < 2; ++c) {                                                     \
      int i = c * 256 + t;                                                            \
      int r = i >> 3;                                                                 \
      int cb = ((i & 7) * 16) ^ ((r & 7) << 4);                                       \
      gload16((gbase) + (size_t)r * (gstride) + cb,                                   \
              (dstLds) + c * 2048 + (t & 192) * 8);                                   \
    }                                                                                 \
  }

__global__ __launch_bounds__(256) void attn_kernel(const u16* __restrict__ qg, const u16* __restrict__ kg,
                                                   const u16* __restrict__ vT, u16* __restrict__ obuf) {
  const int bh = blockIdx.y;
  const int b = bh / kNH, h = bh % kNH;
  const int t = threadIdx.x, lane = t & 63, w = t >> 6;
  const int q0w = blockIdx.x * 128 + w * 32;
  const int ql = lane & 31;
  const int hi = lane >> 5;
  const u16* qb  = qg + (size_t)bh * kN * kD;
  const char* kbB = (const char*)(kg + (size_t)bh * kN * kD);
  const char* vbT = (const char*)(vT + (size_t)bh * kD * kN);

  __shared__ u16 kLds[2 * 4096];
  __shared__ u16 vLds[2 * 4096];

  // Q as B-fragment: Q[q0w+ql][ds*16 + hi*8 + j]
  bf16x8 qf[4];
#pragma unroll
  for (int ds = 0; ds < 4; ++ds)
    qf[ds] = ldg8(&qb[(size_t)(q0w + ql) * kD + ds * 16 + hi * 8]);

  f32x16 o0 = {}, o1 = {};
  float m = -1e30f, l = 0.f;

  STAGE(kLds, kbB, 128)
  STAGE(vLds, vbT, kN * 2)
  __syncthreads();

  for (int ti = 0; ti < kNT; ++ti) {
    const int buf = ti & 1;
    const u16* kL = kLds + buf * 4096;
    const u16* vL = vLds + buf * 4096;
    if (ti + 1 < kNT) {
      const char* kNext = kbB + (size_t)(ti + 1) * 64 * 128;
      const char* vNext = vbT + (size_t)(ti + 1) * 128;
      STAGE(kLds + (buf ^ 1) * 4096, kNext, 128)
      STAGE(vLds + (buf ^ 1) * 4096, vNext, kN * 2)
    }

    // ---- S^T[k][q] = K . Q^T : s0 = k-rows [0,32), s1 = [32,64) of tile
    f32x16 s0 = {}, s1 = {};
#pragma unroll
    for (int ds = 0; ds < 4; ++ds) {
      bf16x8 kf0 = ldsw(kL, ql, ds * 32 + hi * 16);
      bf16x8 kf1 = ldsw(kL, 32 + ql, ds * 32 + hi * 16);
      s0 = __builtin_amdgcn_mfma_f32_32x32x16_bf16(kf0, qf[ds], s0, 0, 0, 0);
      s1 = __builtin_amdgcn_mfma_f32_32x32x16_bf16(kf1, qf[ds], s1, 0, 0, 0);
    }
    // ---- online softmax in exp2 domain: q-row = ql; 32 vals here + 32 in lane^32
    float tmx[16];
#pragma unroll
    for (int r = 0; r < 16; ++r) tmx[r] = fmaxf(s0[r], s1[r]);
#pragma unroll
    for (int st = 8; st; st >>= 1)
#pragma unroll
      for (int r = 0; r < 8; ++r)
        if (r < st) tmx[r] = fmaxf(tmx[r], tmx[r + st]);
    float pmax = fmaxf(tmx[0], __shfl_xor(tmx[0], 32, 64));

    if (!__all(pmax - m <= 8.f)) {  // defer-max: rescale only on real growth
      float mn = fmaxf(m, pmax);
      float al = fexp2(m - mn);
      m = mn;
      l *= al;
      o0 *= al;
      o1 *= al;
    }
#pragma unroll
    for (int r = 0; r < 16; ++r) {
      s0[r] = fexp2(s0[r] - m);
      s1[r] = fexp2(s1[r] - m);
    }
    float tsm[16];
#pragma unroll
    for (int r = 0; r < 16; ++r) tsm[r] = s0[r] + s1[r];
#pragma unroll
    for (int st = 8; st; st >>= 1)
#pragma unroll
      for (int r = 0; r < 8; ++r)
        if (r < st) tsm[r] += tsm[r + st];
    l += tsm[0] + __shfl_xor(tsm[0], 32, 64);

    // ---- PV: O^T[d][q] += V^T . P ; P fragments built in-register
    PV_STEP(s0, 0, 0)
    PV_STEP(s0, 8, 1)
    PV_STEP(s1, 0, 2)
    PV_STEP(s1, 8, 3)

    __syncthreads();
  }

  const float inv = 1.f / l;
  {
    const size_t row = ((size_t)b * kN + q0w + ql) * kC + h * 64;
#pragma unroll
    for (int g = 0; g < 4; ++g) {
      u32x2 pk;
      pk.x = cvtpk(o0[g * 4 + 0] * inv, o0[g * 4 + 1] * inv);
      pk.y = cvtpk(o0[g * 4 + 2] * inv, o0[g * 4 + 3] * inv);
      *reinterpret_cast<u32x2*>(&obuf[row + g * 8 + 4 * hi]) = pk;
    }
#pragma unroll
    for (int g = 0; g < 4; ++g) {
      u32x2 pk;
      pk.x = cvtpk(o1[g * 4 + 0] * inv, o1[g * 4 + 1] * inv);
      pk.y = cvtpk(o1[g * 4 + 2] * inv, o1[g * 4 + 3] * inv);
      *reinterpret_cast<u32x2*>(&obuf[row + 32 + g * 8 + 4 * hi]) = pk;
    }
  }
}

// ---------------- proj (transposed): out[b,c,n] = sum_k W2[c,k]*obuf[b,n,k] + b2[c] + tn[b,n,c] ----------------
__global__ __launch_bounds__(256) void proj_kernel(const u16* __restrict__ obuf, const u16* __restrict__ w2b,
                                                   const float* __restrict__ b2, const u16* __restrict__ tn,
                                                   float* __restrict__ out) {
  __shared__ u16 lAs[128 * 64], lBs[128 * 64];
  const int n0 = blockIdx.x * 128, c0 = blockIdx.y * 128, b = blockIdx.z;
  f32x4 acc[4][4] = {};
  gemm_core(w2b + (size_t)c0 * kC, obuf + ((size_t)b * kN + n0) * kC, acc, lAs, lBs);

  const int t = threadIdx.x, lane = t & 63, w = t >> 6;
  const int wr = w >> 1, wc = w & 1, lr = lane & 15, lg = lane >> 4;
#pragma unroll
  for (int fm = 0; fm < 4; ++fm)
#pragma unroll
    for (int fn = 0; fn < 4; ++fn) {
      int n = n0 + wc * 64 + fn * 16 + lr;
#pragma unroll
      for (int r = 0; r < 4; ++r) {
        int c = c0 + wr * 64 + fm * 16 + lg * 4 + r;
        float val = acc[fm][fn][r] + b2[c] + bf2f(tn[((size_t)b * kN + n) * kC + c]);
        out[((size_t)b * kC + c) * kN + n] = val;
      }
    }
}

extern "C" void kernel_launch(void* const* d_in, const int* in_sizes, int n_in,
                              void* d_out, int out_size, void* d_ws, size_t ws_size,
                              hipStream_t stream) {
  const float* x  = (const float*)d_in[0];
  const float* W1 = (const float*)d_in[1];
  const float* b1 = (const float*)d_in[2];
  const float* W2 = (const float*)d_in[3];
  const float* b2 = (const float*)d_in[4];
  float* out = (float*)d_out;

  const size_t nBNC = (size_t)kM * kC;  // 7,077,888 elements
  u16* tn  = (u16*)d_ws;
  u16* qb  = tn  + nBNC;
  u16* kb  = qb  + nBNC;
  u16* vb  = kb  + nBNC;
  u16* vT  = vb  + nBNC;
  u16* w1b = vT  + nBNC;
  u16* w2b = w1b + (size_t)k3C * kC;
  u16* obuf = vb;  // alias: v is dead after vt_kernel

  ln_kernel<<<dim3(kB * (kN / 64)), dim3(256), 0, stream>>>(x, tn);
  cast_w<<<dim3((k3C * kC + 255) / 256), dim3(256), 0, stream>>>(W1, W2, w1b, w2b);
  qkv_kernel<<<dim3(kM / 128, k3C / 128), dim3(256), 0, stream>>>(tn, w1b, b1, qb, kb, vb);
  vt_kernel<<<dim3(kB * kNH, kN / 64), dim3(256), 0, stream>>>(vb, vT);
  attn_kernel<<<dim3(kN / 128, kB * kNH), dim3(256), 0, stream>>>(qb, kb, vT, obuf);
  proj_kernel<<<dim3(kN / 128, kC / 128, kB), dim3(256), 0, stream>>>(obuf, w2b, b2, tn, out);
}